// Round 5
// baseline (762.876 us; speedup 1.0000x reference)
//
#include <hip/hip_runtime.h>
#include <cmath>

namespace {
constexpr int Bn = 128, Tn = 128, BTn = Bn * Tn;
constexpr int CONTn = 16, HIDn = 128, EMBn = 64;
constexpr int Kn = 8192, CEn = 6, VSPn = 2000, VLCn = 32, FINn = 3 * HIDn;
constexpr int VQ_CHUNKS = 16;             // 512 codes per chunk
constexpr int VSP_PAD = 2048;             // padded vocab for MFMA tiles

// ---- workspace layout (float units) ----
constexpr size_t WS_NAIP2 = 0;                               // B*HID
constexpr size_t WS_ZE    = WS_NAIP2 + (size_t)Bn * HIDn;    // BT*EMB
constexpr size_t WS_ZQ    = WS_ZE + (size_t)BTn * EMBn;      // BT*EMB
constexpr size_t WS_H     = WS_ZQ + (size_t)BTn * EMBn;      // BT*HID
constexpr size_t WS_ESQ   = WS_H + (size_t)BTn * HIDn;       // K
constexpr size_t WS_PART  = WS_ESQ + Kn;                     // 64 partial loss sums
constexpr size_t WS_CNT   = WS_PART + 64;                    // K ints
constexpr size_t WS_PD    = WS_CNT + Kn;                     // VQ_CHUNKS*BT floats
constexpr size_t WS_PI    = WS_PD + (size_t)VQ_CHUNKS * BTn; // VQ_CHUNKS*BT ints
constexpr size_t WS_HBF   = WS_PI + (size_t)VQ_CHUNKS * BTn; // BT*HID ushorts = BT*64 floats
constexpr size_t WS_WBF   = WS_HBF + (size_t)BTn * 64;       // VSP_PAD*HID ushorts
constexpr size_t WS_END   = WS_WBF + (size_t)VSP_PAD * HIDn / 2;

// ---- output layout (float units) ----
constexpr size_t O_CONT = 0;
constexpr size_t O_SP   = O_CONT + (size_t)BTn * CONTn;
constexpr size_t O_LC   = O_SP + (size_t)BTn * VSPn;
constexpr size_t O_CAN  = O_LC + (size_t)BTn * VLCn;
constexpr size_t O_IDX  = O_CAN + Bn;
constexpr size_t O_LOSS = O_IDX + BTn;
constexpr size_t O_PPL  = O_LOSS + 1;
} // namespace

typedef __attribute__((ext_vector_type(8))) short short8v;  // 8 bf16 = 4 VGPR
typedef __attribute__((ext_vector_type(4))) float f32x4;

__device__ __forceinline__ float nan0(float v) {
    return __builtin_isfinite(v) ? v : 0.0f;
}
__device__ __forceinline__ float dot4(float4 a, float4 b) {
    return a.x * b.x + a.y * b.y + a.z * b.z + a.w * b.w;
}
__device__ __forceinline__ unsigned short f2bf(float f) { // RNE, finite-only
    union { float f; unsigned u; } v{f};
    unsigned r = v.u + 0x7FFFu + ((v.u >> 16) & 1u);
    return (unsigned short)(r >> 16);
}

// ---------------------------------------------------------------- K0: zero counts + codebook row norms
__global__ __launch_bounds__(256) void k_esq_zero(const float* __restrict__ cb,
                                                  float* __restrict__ e_sq,
                                                  int* __restrict__ counts) {
    int i = blockIdx.x * 256 + threadIdx.x;
    if (i < Kn) {
        counts[i] = 0;
        const float4* r = (const float4*)(cb + (size_t)i * EMBn);
        float s = 0.f;
#pragma unroll
        for (int j = 0; j < 16; ++j) { float4 v = r[j]; s += dot4(v, v); }
        e_sq[i] = s;
    }
}

// ---------------------------------------------------------------- K0b: sp_head_w -> bf16, padded to 2048 rows
__global__ __launch_bounds__(256) void k_wcast(const float* __restrict__ w,
                                               unsigned short* __restrict__ wbf) {
    int i = blockIdx.x * 256 + threadIdx.x;      // float4 index; 32 per row
    int v = i >> 5;
    unsigned short u[4] = {0, 0, 0, 0};
    if (v < VSPn) {
        float4 x = ((const float4*)w)[i];
        u[0] = f2bf(x.x); u[1] = f2bf(x.y); u[2] = f2bf(x.z); u[3] = f2bf(x.w);
    }
    *(uint2*)(wbf + (size_t)i * 4) = *(const uint2*)u;
}

// ---------------------------------------------------------------- K1: naip conv + proj -> naip2 (B x HID)
__global__ __launch_bounds__(128) void k_naip(const float* __restrict__ naip,
                                              const float* __restrict__ conv_w,
                                              const float* __restrict__ conv_b,
                                              const float* __restrict__ pw,
                                              const float* __restrict__ pb,
                                              float* __restrict__ naip2) {
    int b = blockIdx.x, o = threadIdx.x;
    __shared__ float feat[HIDn];
    float acc = conv_b[o];
#pragma unroll
    for (int i = 0; i < 9; ++i) acc += nan0(naip[b * 9 + i]) * conv_w[o * 9 + i];
    feat[o] = fmaxf(acc, 0.f);
    __syncthreads();
    float a2 = pb[o];
    const float4* wr = (const float4*)(pw + (size_t)o * HIDn);
    const float4* fr = (const float4*)feat;
#pragma unroll
    for (int j = 0; j < 32; ++j) a2 += dot4(fr[j], wr[j]);
    naip2[(size_t)b * HIDn + o] = a2;
}

// ---------------------------------------------------------------- K2: fused inputs -> z_e (BT x EMB)
__global__ __launch_bounds__(256) void k_ze(
    const float* __restrict__ cont, const int* __restrict__ cat,
    const float* __restrict__ emb_sp, const float* __restrict__ emb_lc,
    const float* __restrict__ cpw, const float* __restrict__ cpb,
    const float* __restrict__ caw, const float* __restrict__ cab,
    const float* __restrict__ f1w, const float* __restrict__ f1b,
    const float* __restrict__ f2w, const float* __restrict__ f2b,
    const float* __restrict__ naip2, float* __restrict__ z_e) {
    const int tok0 = blockIdx.x * 16;
    const int tid = threadIdx.x;
    __shared__ float fused[16][FINn + 4];
    __shared__ float h1[16][HIDn + 4];

    for (int idx = tid; idx < 16 * HIDn; idx += 256) {
        int t = idx >> 7, j = idx & 127;
        int b = (tok0 + t) / Tn;
        fused[t][j] = naip2[(size_t)b * HIDn + j];
    }
    for (int idx = tid; idx < 16 * HIDn; idx += 256) {
        int t = idx >> 7, o = idx & 127;
        int tok = tok0 + t;
        const float4* cp = (const float4*)(cont + (size_t)tok * CONTn);
        const float4* wr = (const float4*)(cpw + (size_t)o * CONTn);
        float a = cpb[o];
#pragma unroll
        for (int q = 0; q < 4; ++q) {
            float4 c4 = cp[q], w4 = wr[q];
            a += nan0(c4.x) * w4.x + nan0(c4.y) * w4.y + nan0(c4.z) * w4.z + nan0(c4.w) * w4.w;
        }
        fused[t][HIDn + o] = a;
    }
    for (int idx = tid; idx < 16 * HIDn; idx += 256) {
        int t = idx >> 7, o = idx & 127;
        int tok = tok0 + t;
        int c0 = cat[tok * 2], c1 = cat[tok * 2 + 1];
        const float* e0 = emb_sp + (size_t)c0 * CEn;
        const float* e1 = emb_lc + (size_t)c1 * CEn;
        const float* wr = caw + (size_t)o * (2 * CEn);
        float a = cab[o];
#pragma unroll
        for (int i = 0; i < CEn; ++i) a += e0[i] * wr[i];
#pragma unroll
        for (int i = 0; i < CEn; ++i) a += e1[i] * wr[CEn + i];
        fused[t][2 * HIDn + o] = a;
    }
    __syncthreads();
    {
        int o = tid >> 1, half = tid & 1;
        float acc[8];
        float bv = f1b[o];
#pragma unroll
        for (int t = 0; t < 8; ++t) acc[t] = bv;
        const float4* wr = (const float4*)(f1w + (size_t)o * FINn);
        for (int kk = 0; kk < FINn / 4; ++kk) {
            float4 w = wr[kk];
#pragma unroll
            for (int t = 0; t < 8; ++t) {
                float4 f = ((const float4*)&fused[half * 8 + t][0])[kk];
                acc[t] += dot4(f, w);
            }
        }
#pragma unroll
        for (int t = 0; t < 8; ++t) h1[half * 8 + t][o] = fmaxf(acc[t], 0.f);
    }
    __syncthreads();
    {
        int o = tid & 63, tg = tid >> 6;
        float acc[4];
        float bv = f2b[o];
#pragma unroll
        for (int t = 0; t < 4; ++t) acc[t] = bv;
        const float4* wr = (const float4*)(f2w + (size_t)o * HIDn);
        for (int kk = 0; kk < HIDn / 4; ++kk) {
            float4 w = wr[kk];
#pragma unroll
            for (int t = 0; t < 4; ++t) {
                float4 f = ((const float4*)&h1[tg * 4 + t][0])[kk];
                acc[t] += dot4(f, w);
            }
        }
#pragma unroll
        for (int t = 0; t < 4; ++t) z_e[(size_t)(tok0 + tg * 4 + t) * EMBn + o] = acc[t];
    }
}

// ---------------------------------------------------------------- K3a: VQ partial argmin, z-in-VGPR, uniform code loads
// grid (VQ_CHUNKS, BT/256); block 256. Thread owns one token (z in 64 VGPRs);
// code row address is wave-uniform -> scalar loads (SMEM pipe), no LDS at all.
__global__ __launch_bounds__(256, 4) void k_vq_partial(
    const float* __restrict__ z_e, const float* __restrict__ cb,
    const float* __restrict__ e_sq, float* __restrict__ pd, int* __restrict__ pi) {
    const int tid = threadIdx.x;
    const int tok = blockIdx.y * 256 + tid;
    const int c_base = blockIdx.x * (Kn / VQ_CHUNKS);

    float4 z[16];
    const float4* zr = (const float4*)(z_e + (size_t)tok * EMBn);
#pragma unroll
    for (int q = 0; q < 16; ++q) z[q] = zr[q];

    float bd = INFINITY;
    int bi = c_base;
    const float* cbp = cb + (size_t)c_base * EMBn;
    const float* esp = e_sq + c_base;

#pragma unroll 2
    for (int c = 0; c < Kn / VQ_CHUNKS; ++c) {
        const float4* cp = (const float4*)(cbp + (size_t)c * EMBn);
        float a0 = 0.f, a1 = 0.f, a2 = 0.f, a3 = 0.f;
#pragma unroll
        for (int q = 0; q < 4; ++q) {
            a0 += dot4(z[q * 4 + 0], cp[q * 4 + 0]);
            a1 += dot4(z[q * 4 + 1], cp[q * 4 + 1]);
            a2 += dot4(z[q * 4 + 2], cp[q * 4 + 2]);
            a3 += dot4(z[q * 4 + 3], cp[q * 4 + 3]);
        }
        float d = esp[c] - 2.f * ((a0 + a1) + (a2 + a3));
        if (d < bd) { bd = d; bi = c_base + c; } // codes ascending -> lowest-index tie-break
    }
    pd[(size_t)blockIdx.x * BTn + tok] = bd;
    pi[(size_t)blockIdx.x * BTn + tok] = bi;
}

// ---------------------------------------------------------------- K3b: merge chunks, gather z_q, counts, loss
__global__ __launch_bounds__(256) void k_vq_reduce(
    const float* __restrict__ pd, const int* __restrict__ pi,
    const float* __restrict__ z_e, const float* __restrict__ cb,
    float* __restrict__ z_q, float* __restrict__ idx_out,
    int* __restrict__ counts, float* __restrict__ partials) {
    const int tid = threadIdx.x;
    const int tok = blockIdx.x * 256 + tid;
    float best = pd[tok];
    int b_ = pi[tok];
#pragma unroll
    for (int c = 1; c < VQ_CHUNKS; ++c) {
        float d = pd[(size_t)c * BTn + tok];
        int i2 = pi[(size_t)c * BTn + tok];
        if (d < best || (d == best && i2 < b_)) { best = d; b_ = i2; }
    }
    idx_out[tok] = (float)b_;
    atomicAdd(&counts[b_], 1);

    float lsum = 0.f;
    const float4* cr = (const float4*)(cb + (size_t)b_ * EMBn);
    const float4* zr = (const float4*)(z_e + (size_t)tok * EMBn);
    float4* qr = (float4*)(z_q + (size_t)tok * EMBn);
#pragma unroll
    for (int q = 0; q < 16; ++q) {
        float4 cq = cr[q];
        qr[q] = cq;
        float4 zz = zr[q];
        float dx = zz.x - cq.x, dy = zz.y - cq.y, dz = zz.z - cq.z, dw = zz.w - cq.w;
        lsum += dx * dx + dy * dy + dz * dz + dw * dw;
    }
    __shared__ float red[256];
    red[tid] = lsum;
    __syncthreads();
    for (int sdist = 128; sdist > 0; sdist >>= 1) {
        if (tid < sdist) red[tid] += red[tid + sdist];
        __syncthreads();
    }
    if (tid == 0) partials[blockIdx.x] = red[0];
}

// ---------------------------------------------------------------- K4: backbone + small heads (+ h in bf16)
__global__ __launch_bounds__(256) void k_backbone(
    const float* __restrict__ z_q,
    const float* __restrict__ bb1w, const float* __restrict__ bb1b,
    const float* __restrict__ bb2w, const float* __restrict__ bb2b,
    const float* __restrict__ chw, const float* __restrict__ chb,
    const float* __restrict__ lcw, const float* __restrict__ lcb,
    float* __restrict__ h_out, unsigned short* __restrict__ hbf_out,
    float* __restrict__ cont_rec, float* __restrict__ lc_out) {
    const int tid = threadIdx.x;
    const int tok0 = blockIdx.x * 16;
    __shared__ float zq[16][68];
    __shared__ float h1[16][HIDn + 4];
    __shared__ float h2[16][HIDn + 4];
    {
        int t = tid >> 4, q = tid & 15;
        ((float4*)&zq[t][0])[q] = ((const float4*)(z_q + (size_t)(tok0 + t) * EMBn))[q];
    }
    __syncthreads();
    {
        int o = tid >> 1, half = tid & 1;
        float acc[8];
        float bv = bb1b[o];
#pragma unroll
        for (int t = 0; t < 8; ++t) acc[t] = bv;
        const float4* wr = (const float4*)(bb1w + (size_t)o * EMBn);
#pragma unroll
        for (int kk = 0; kk < 16; ++kk) {
            float4 w = wr[kk];
#pragma unroll
            for (int t = 0; t < 8; ++t) acc[t] += dot4(((const float4*)&zq[half * 8 + t][0])[kk], w);
        }
#pragma unroll
        for (int t = 0; t < 8; ++t) h1[half * 8 + t][o] = fmaxf(acc[t], 0.f);
    }
    __syncthreads();
    {
        int o = tid >> 1, half = tid & 1;
        float acc[8];
        float bv = bb2b[o];
#pragma unroll
        for (int t = 0; t < 8; ++t) acc[t] = bv;
        const float4* wr = (const float4*)(bb2w + (size_t)o * HIDn);
        for (int kk = 0; kk < 32; ++kk) {
            float4 w = wr[kk];
#pragma unroll
            for (int t = 0; t < 8; ++t) acc[t] += dot4(((const float4*)&h1[half * 8 + t][0])[kk], w);
        }
#pragma unroll
        for (int t = 0; t < 8; ++t) {
            float v = fmaxf(acc[t], 0.f);
            h2[half * 8 + t][o] = v;
            h_out[(size_t)(tok0 + half * 8 + t) * HIDn + o] = v;
            hbf_out[(size_t)(tok0 + half * 8 + t) * HIDn + o] = f2bf(v);
        }
    }
    __syncthreads();
    {
        int t = tid >> 4, o = tid & 15;
        float a = chb[o];
        const float4* wr = (const float4*)(chw + (size_t)o * HIDn);
#pragma unroll
        for (int kk = 0; kk < 32; ++kk) a += dot4(((const float4*)&h2[t][0])[kk], wr[kk]);
        cont_rec[(size_t)(tok0 + t) * CONTn + o] = a;
    }
    for (int idx = tid; idx < 16 * 32; idx += 256) {
        int t = idx >> 5, o = idx & 31;
        float a = lcb[o];
        const float4* wr = (const float4*)(lcw + (size_t)o * HIDn);
#pragma unroll
        for (int kk = 0; kk < 32; ++kk) a += dot4(((const float4*)&h2[t][0])[kk], wr[kk]);
        lc_out[(size_t)(tok0 + t) * VLCn + o] = a;
    }
}

// ---------------------------------------------------------------- K5: sp_logits via bf16 MFMA, direct-from-L2 frags
// grid (16, 128); block 256 = 4 waves; block tile 128 tok x 128 vocab; wave tile 64x64.
__global__ __launch_bounds__(256, 3) void k_sp_mfma(
    const unsigned short* __restrict__ hbf, const unsigned short* __restrict__ wbf,
    const float* __restrict__ bias, float* __restrict__ out) {
    const int tid = threadIdx.x;
    const int lane = tid & 63;
    const int wid = tid >> 6;
    const int tok_w = blockIdx.y * 128 + (wid & 1) * 64;
    const int v_w = blockIdx.x * 128 + (wid >> 1) * 64;

    const int lrow = lane & 15;
    const int lk = (lane >> 4) * 8;

    const unsigned short* ha = hbf + (size_t)(tok_w + lrow) * HIDn + lk;
    const unsigned short* wa = wbf + (size_t)(v_w + lrow) * HIDn + lk;

    f32x4 acc[4][4];
#pragma unroll
    for (int m = 0; m < 4; ++m)
#pragma unroll
        for (int n = 0; n < 4; ++n) acc[m][n] = (f32x4){0.f, 0.f, 0.f, 0.f};

#pragma unroll
    for (int ks = 0; ks < 4; ++ks) {
        const int kk = ks * 32;
        short8v a[4], b[4];
#pragma unroll
        for (int m = 0; m < 4; ++m)
            a[m] = *(const short8v*)(ha + (size_t)m * 16 * HIDn + kk);
#pragma unroll
        for (int n = 0; n < 4; ++n)
            b[n] = *(const short8v*)(wa + (size_t)n * 16 * HIDn + kk);
#pragma unroll
        for (int m = 0; m < 4; ++m)
#pragma unroll
            for (int n = 0; n < 4; ++n)
                acc[m][n] = __builtin_amdgcn_mfma_f32_16x16x32_bf16(a[m], b[n], acc[m][n], 0, 0, 0);
    }

    // epilogue: C[row = (lane>>4)*4 + r][col = lane&15] per 16x16 frag
    const int r0 = (lane >> 4) * 4;
#pragma unroll
    for (int n = 0; n < 4; ++n) {
        const int col = v_w + n * 16 + lrow;
        if (col < VSPn) {
            const float bv = bias[col];
#pragma unroll
            for (int m = 0; m < 4; ++m) {
                const int row = tok_w + m * 16 + r0;
#pragma unroll
                for (int r = 0; r < 4; ++r)
                    out[(size_t)(row + r) * VSPn + col] = acc[m][n][r] + bv;
            }
        }
    }
}

// ---------------------------------------------------------------- K6: canopy head on h[:, -1, :]
__global__ __launch_bounds__(128) void k_canopy(const float* __restrict__ h,
                                                const float* __restrict__ w1,
                                                const float* __restrict__ b1,
                                                const float* __restrict__ w2,
                                                const float* __restrict__ b2,
                                                float* __restrict__ can) {
    int b = blockIdx.x, o = threadIdx.x;
    __shared__ float r[128];
    const float4* hr = (const float4*)(h + (size_t)(b * Tn + Tn - 1) * HIDn);
    const float4* wr = (const float4*)(w1 + (size_t)o * HIDn);
    float a = b1[o];
#pragma unroll
    for (int kk = 0; kk < 32; ++kk) a += dot4(hr[kk], wr[kk]);
    r[o] = fmaxf(a, 0.f) * w2[o];
    __syncthreads();
    for (int s = 64; s > 0; s >>= 1) {
        if (o < s) r[o] += r[o + s];
        __syncthreads();
    }
    if (o == 0) can[b] = r[0] + b2[0];
}

// ---------------------------------------------------------------- K7: loss + perplexity
__global__ __launch_bounds__(256) void k_finalize(const float* __restrict__ partials,
                                                  const int* __restrict__ counts,
                                                  float* __restrict__ out_loss,
                                                  float* __restrict__ out_ppl) {
    const int tid = threadIdx.x;
    __shared__ float red[256];
    red[tid] = (tid < 64) ? partials[tid] : 0.f;
    __syncthreads();
    for (int s = 128; s > 0; s >>= 1) {
        if (tid < s) red[tid] += red[tid + s];
        __syncthreads();
    }
    float total = red[0];
    __syncthreads();
    float e = 0.f;
    for (int i = tid; i < Kn; i += 256) {
        float p = (float)counts[i] * (1.0f / BTn);
        e += p * logf(p + 1e-12f);
    }
    red[tid] = e;
    __syncthreads();
    for (int s = 128; s > 0; s >>= 1) {
        if (tid < s) red[tid] += red[tid + s];
        __syncthreads();
    }
    if (tid == 0) {
        out_loss[0] = 1.25f * total / (float)((size_t)BTn * EMBn);
        out_ppl[0] = expf(-red[0]);
    }
}

// ----------------------------------------------------------------
extern "C" void kernel_launch(void* const* d_in, const int* in_sizes, int n_in,
                              void* d_out, int out_size, void* d_ws, size_t ws_size,
                              hipStream_t stream) {
    const float* cont = (const float*)d_in[0];
    const float* naip = (const float*)d_in[1];
    const int* cat = (const int*)d_in[2];
    const float* emb_sp = (const float*)d_in[3];
    const float* emb_lc = (const float*)d_in[4];
    const float* conv_w = (const float*)d_in[5];
    const float* conv_b = (const float*)d_in[6];
    const float* npw = (const float*)d_in[7];
    const float* npb = (const float*)d_in[8];
    const float* cpw = (const float*)d_in[9];
    const float* cpb = (const float*)d_in[10];
    const float* caw = (const float*)d_in[11];
    const float* cab = (const float*)d_in[12];
    const float* f1w = (const float*)d_in[13];
    const float* f1b = (const float*)d_in[14];
    const float* f2w = (const float*)d_in[15];
    const float* f2b = (const float*)d_in[16];
    const float* cb = (const float*)d_in[17];
    const float* bb1w = (const float*)d_in[18];
    const float* bb1b = (const float*)d_in[19];
    const float* bb2w = (const float*)d_in[20];
    const float* bb2b = (const float*)d_in[21];
    const float* chw = (const float*)d_in[22];
    const float* chb = (const float*)d_in[23];
    const float* spw = (const float*)d_in[24];
    const float* spb = (const float*)d_in[25];
    const float* lcw = (const float*)d_in[26];
    const float* lcb = (const float*)d_in[27];
    const float* c1w = (const float*)d_in[28];
    const float* c1b = (const float*)d_in[29];
    const float* c2w = (const float*)d_in[30];
    const float* c2b = (const float*)d_in[31];

    float* out = (float*)d_out;
    float* ws = (float*)d_ws;
    float* naip2 = ws + WS_NAIP2;
    float* z_e = ws + WS_ZE;
    float* z_q = ws + WS_ZQ;
    float* h = ws + WS_H;
    float* e_sq = ws + WS_ESQ;
    float* parts = ws + WS_PART;
    int* counts = (int*)(ws + WS_CNT);
    float* pd = ws + WS_PD;
    int* pi = (int*)(ws + WS_PI);
    unsigned short* hbf = (unsigned short*)(ws + WS_HBF);
    unsigned short* wbf = (unsigned short*)(ws + WS_WBF);

    k_esq_zero<<<dim3(Kn / 256), dim3(256), 0, stream>>>(cb, e_sq, counts);
    k_wcast<<<dim3(VSP_PAD * HIDn / 4 / 256), dim3(256), 0, stream>>>(spw, wbf);
    k_naip<<<dim3(Bn), dim3(128), 0, stream>>>(naip, conv_w, conv_b, npw, npb, naip2);
    k_ze<<<dim3(BTn / 16), dim3(256), 0, stream>>>(cont, cat, emb_sp, emb_lc, cpw, cpb, caw, cab,
                                                   f1w, f1b, f2w, f2b, naip2, z_e);
    k_vq_partial<<<dim3(VQ_CHUNKS, BTn / 256), dim3(256), 0, stream>>>(z_e, cb, e_sq, pd, pi);
    k_vq_reduce<<<dim3(BTn / 256), dim3(256), 0, stream>>>(pd, pi, z_e, cb, z_q, out + O_IDX,
                                                           counts, parts);
    k_backbone<<<dim3(BTn / 16), dim3(256), 0, stream>>>(z_q, bb1w, bb1b, bb2w, bb2b, chw, chb,
                                                         lcw, lcb, h, hbf, out + O_CONT, out + O_LC);
    k_sp_mfma<<<dim3(VSP_PAD / 128, BTn / 128), dim3(256), 0, stream>>>(hbf, wbf, spb, out + O_SP);
    k_canopy<<<dim3(Bn), dim3(128), 0, stream>>>(h, c1w, c1b, c2w, c2b, out + O_CAN);
    k_finalize<<<dim3(1), dim3(256), 0, stream>>>(parts, counts, out + O_LOSS, out + O_PPL);
}

// Round 6
// 422.521 us; speedup vs baseline: 1.8055x; 1.8055x over previous
//
#include <hip/hip_runtime.h>
#include <cmath>

namespace {
constexpr int Bn = 128, Tn = 128, BTn = Bn * Tn;
constexpr int CONTn = 16, HIDn = 128, EMBn = 64;
constexpr int Kn = 8192, CEn = 6, VSPn = 2000, VLCn = 32, FINn = 3 * HIDn;
constexpr int VSP_PAD = 2048;             // padded vocab for MFMA tiles
constexpr int CAP = 64;                   // max stored VQ candidates per token
constexpr float EPSC = 0.02f;             // rigorous bf16 interval coefficient (2^-6 * 1.28)

// ---- workspace layout (float units) ----
constexpr size_t WS_NAIP2 = 0;                               // B*HID
constexpr size_t WS_ZE    = WS_NAIP2 + (size_t)Bn * HIDn;    // BT*EMB
constexpr size_t WS_ZQ    = WS_ZE + (size_t)BTn * EMBn;      // BT*EMB
constexpr size_t WS_H     = WS_ZQ + (size_t)BTn * EMBn;      // BT*HID
constexpr size_t WS_ESQ   = WS_H + (size_t)BTn * HIDn;       // K
constexpr size_t WS_PART  = WS_ESQ + Kn;                     // BT/4 partial loss sums
constexpr size_t WS_CNTK  = WS_PART + BTn / 4;               // K ints (code counts)
constexpr size_t WS_CNTT  = WS_CNTK + Kn;                    // BT ints (candidate counts)
constexpr size_t WS_Q     = WS_CNTT + BTn;                   // BT floats (eps per token)
constexpr size_t WS_CAND  = WS_Q + BTn;                      // BT*CAP ints
constexpr size_t WS_ZBF   = WS_CAND + (size_t)BTn * CAP;     // BT*EMB ushort
constexpr size_t WS_CBBF  = WS_ZBF + (size_t)BTn * EMBn / 2; // K*EMB ushort
constexpr size_t WS_HBF   = WS_CBBF + (size_t)Kn * EMBn / 2; // BT*HID ushort
constexpr size_t WS_WBF   = WS_HBF + (size_t)BTn * HIDn / 2; // VSP_PAD*HID ushort

// ---- output layout (float units) ----
constexpr size_t O_CONT = 0;
constexpr size_t O_SP   = O_CONT + (size_t)BTn * CONTn;
constexpr size_t O_LC   = O_SP + (size_t)BTn * VSPn;
constexpr size_t O_CAN  = O_LC + (size_t)BTn * VLCn;
constexpr size_t O_IDX  = O_CAN + Bn;
constexpr size_t O_LOSS = O_IDX + BTn;
constexpr size_t O_PPL  = O_LOSS + 1;
} // namespace

typedef __attribute__((ext_vector_type(8))) short short8v;  // 8 bf16 = 4 VGPR
typedef __attribute__((ext_vector_type(4))) float f32x4;

__device__ __forceinline__ float nan0(float v) {
    return __builtin_isfinite(v) ? v : 0.0f;
}
__device__ __forceinline__ float dot4(float4 a, float4 b) {
    return a.x * b.x + a.y * b.y + a.z * b.z + a.w * b.w;
}
__device__ __forceinline__ unsigned short f2bf(float f) { // RNE, finite-only
    union { float f; unsigned u; } v{f};
    unsigned r = v.u + 0x7FFFu + ((v.u >> 16) & 1u);
    return (unsigned short)(r >> 16);
}

// ---------------------------------------------------------------- K0: zero code counts + e_sq + bf16 codebook
__global__ __launch_bounds__(256) void k_esq_zero(const float* __restrict__ cb,
                                                  float* __restrict__ e_sq,
                                                  int* __restrict__ counts,
                                                  unsigned short* __restrict__ cbbf) {
    int i = blockIdx.x * 256 + threadIdx.x;
    if (i < Kn) {
        counts[i] = 0;
        const float4* r = (const float4*)(cb + (size_t)i * EMBn);
        float s = 0.f;
#pragma unroll
        for (int j = 0; j < 16; ++j) {
            float4 v = r[j];
            s += dot4(v, v);
            unsigned short u[4] = {f2bf(v.x), f2bf(v.y), f2bf(v.z), f2bf(v.w)};
            *(uint2*)(cbbf + (size_t)i * EMBn + j * 4) = *(const uint2*)u;
        }
        e_sq[i] = s;
    }
}

// ---------------------------------------------------------------- K0b: sp_head_w -> bf16, padded to 2048 rows
__global__ __launch_bounds__(256) void k_wcast(const float* __restrict__ w,
                                               unsigned short* __restrict__ wbf) {
    int i = blockIdx.x * 256 + threadIdx.x;      // float4 index; 32 per row
    int v = i >> 5;
    unsigned short u[4] = {0, 0, 0, 0};
    if (v < VSPn) {
        float4 x = ((const float4*)w)[i];
        u[0] = f2bf(x.x); u[1] = f2bf(x.y); u[2] = f2bf(x.z); u[3] = f2bf(x.w);
    }
    *(uint2*)(wbf + (size_t)i * 4) = *(const uint2*)u;
}

// ---------------------------------------------------------------- K1: naip conv + proj -> naip2 (B x HID)
__global__ __launch_bounds__(128) void k_naip(const float* __restrict__ naip,
                                              const float* __restrict__ conv_w,
                                              const float* __restrict__ conv_b,
                                              const float* __restrict__ pw,
                                              const float* __restrict__ pb,
                                              float* __restrict__ naip2) {
    int b = blockIdx.x, o = threadIdx.x;
    __shared__ float feat[HIDn];
    float acc = conv_b[o];
#pragma unroll
    for (int i = 0; i < 9; ++i) acc += nan0(naip[b * 9 + i]) * conv_w[o * 9 + i];
    feat[o] = fmaxf(acc, 0.f);
    __syncthreads();
    float a2 = pb[o];
    const float4* wr = (const float4*)(pw + (size_t)o * HIDn);
    const float4* fr = (const float4*)feat;
#pragma unroll
    for (int j = 0; j < 32; ++j) a2 += dot4(fr[j], wr[j]);
    naip2[(size_t)b * HIDn + o] = a2;
}

// ---------------------------------------------------------------- K2: fused inputs -> z_e (BT x EMB)
__global__ __launch_bounds__(256) void k_ze(
    const float* __restrict__ cont, const int* __restrict__ cat,
    const float* __restrict__ emb_sp, const float* __restrict__ emb_lc,
    const float* __restrict__ cpw, const float* __restrict__ cpb,
    const float* __restrict__ caw, const float* __restrict__ cab,
    const float* __restrict__ f1w, const float* __restrict__ f1b,
    const float* __restrict__ f2w, const float* __restrict__ f2b,
    const float* __restrict__ naip2, float* __restrict__ z_e) {
    const int tok0 = blockIdx.x * 16;
    const int tid = threadIdx.x;
    __shared__ float fused[16][FINn + 4];
    __shared__ float h1[16][HIDn + 4];

    for (int idx = tid; idx < 16 * HIDn; idx += 256) {
        int t = idx >> 7, j = idx & 127;
        int b = (tok0 + t) / Tn;
        fused[t][j] = naip2[(size_t)b * HIDn + j];
    }
    for (int idx = tid; idx < 16 * HIDn; idx += 256) {
        int t = idx >> 7, o = idx & 127;
        int tok = tok0 + t;
        const float4* cp = (const float4*)(cont + (size_t)tok * CONTn);
        const float4* wr = (const float4*)(cpw + (size_t)o * CONTn);
        float a = cpb[o];
#pragma unroll
        for (int q = 0; q < 4; ++q) {
            float4 c4 = cp[q], w4 = wr[q];
            a += nan0(c4.x) * w4.x + nan0(c4.y) * w4.y + nan0(c4.z) * w4.z + nan0(c4.w) * w4.w;
        }
        fused[t][HIDn + o] = a;
    }
    for (int idx = tid; idx < 16 * HIDn; idx += 256) {
        int t = idx >> 7, o = idx & 127;
        int tok = tok0 + t;
        int c0 = cat[tok * 2], c1 = cat[tok * 2 + 1];
        const float* e0 = emb_sp + (size_t)c0 * CEn;
        const float* e1 = emb_lc + (size_t)c1 * CEn;
        const float* wr = caw + (size_t)o * (2 * CEn);
        float a = cab[o];
#pragma unroll
        for (int i = 0; i < CEn; ++i) a += e0[i] * wr[i];
#pragma unroll
        for (int i = 0; i < CEn; ++i) a += e1[i] * wr[CEn + i];
        fused[t][2 * HIDn + o] = a;
    }
    __syncthreads();
    {
        int o = tid >> 1, half = tid & 1;
        float acc[8];
        float bv = f1b[o];
#pragma unroll
        for (int t = 0; t < 8; ++t) acc[t] = bv;
        const float4* wr = (const float4*)(f1w + (size_t)o * FINn);
        for (int kk = 0; kk < FINn / 4; ++kk) {
            float4 w = wr[kk];
#pragma unroll
            for (int t = 0; t < 8; ++t) {
                float4 f = ((const float4*)&fused[half * 8 + t][0])[kk];
                acc[t] += dot4(f, w);
            }
        }
#pragma unroll
        for (int t = 0; t < 8; ++t) h1[half * 8 + t][o] = fmaxf(acc[t], 0.f);
    }
    __syncthreads();
    {
        int o = tid & 63, tg = tid >> 6;
        float acc[4];
        float bv = f2b[o];
#pragma unroll
        for (int t = 0; t < 4; ++t) acc[t] = bv;
        const float4* wr = (const float4*)(f2w + (size_t)o * HIDn);
        for (int kk = 0; kk < HIDn / 4; ++kk) {
            float4 w = wr[kk];
#pragma unroll
            for (int t = 0; t < 4; ++t) {
                float4 f = ((const float4*)&h1[tg * 4 + t][0])[kk];
                acc[t] += dot4(f, w);
            }
        }
#pragma unroll
        for (int t = 0; t < 4; ++t) z_e[(size_t)(tok0 + tg * 4 + t) * EMBn + o] = acc[t];
    }
}

// ---------------------------------------------------------------- K3p: z -> bf16, per-token eps, zero cand counts
// block 256 = 4 tokens x 64 lanes
__global__ __launch_bounds__(256) void k_zprep(const float* __restrict__ z_e,
                                               unsigned short* __restrict__ zbf,
                                               float* __restrict__ qtok,
                                               int* __restrict__ cntT) {
    const int lane = threadIdx.x & 63;
    const int tg = threadIdx.x >> 6;
    const int t = blockIdx.x * 4 + tg;
    float zv = z_e[(size_t)t * EMBn + lane];
    zbf[(size_t)t * EMBn + lane] = f2bf(zv);
    float s = zv * zv;
#pragma unroll
    for (int off = 32; off > 0; off >>= 1) s += __shfl_xor(s, off);
    if (lane == 0) {
        qtok[t] = EPSC * sqrtf(s);
        cntT[t] = 0;
    }
}

// ---------------------------------------------------------------- K3a: VQ bf16-MFMA scoring + interval candidate collect
// grid (Kn/512, BTn/64); block 512 = 8 waves; wave = 64 codes x 64 tokens.
// A = codebook rows (M=codes), B = z rows (N=tokens); C col=lane&15 (token), row=(lane>>4)*4+r (code).
__global__ __launch_bounds__(512) void k_vq_score(
    const unsigned short* __restrict__ zbf, const unsigned short* __restrict__ cbbf,
    const float* __restrict__ e_sq, const float* __restrict__ qtok,
    int* __restrict__ cntT, int* __restrict__ cand) {
    const int tid = threadIdx.x;
    const int lane = tid & 63;
    const int wid = tid >> 6;          // 0..7
    const int lrow = lane & 15;
    const int g = lane >> 4;           // 0..3
    const int tok0 = blockIdx.y * 64;
    const int cw = blockIdx.x * 512 + wid * 64;

    __shared__ float tau[8][64];

    // fragment loads (direct from L2-resident bf16 tables)
    short8v bz[4][2], ac[4][2];
#pragma unroll
    for (int n = 0; n < 4; ++n)
#pragma unroll
        for (int kc = 0; kc < 2; ++kc)
            bz[n][kc] = *(const short8v*)(zbf + (size_t)(tok0 + n * 16 + lrow) * EMBn + kc * 32 + g * 8);
#pragma unroll
    for (int m = 0; m < 4; ++m)
#pragma unroll
        for (int kc = 0; kc < 2; ++kc)
            ac[m][kc] = *(const short8v*)(cbbf + (size_t)(cw + m * 16 + lrow) * EMBn + kc * 32 + g * 8);

    f32x4 acc[4][4];
#pragma unroll
    for (int m = 0; m < 4; ++m)
#pragma unroll
        for (int n = 0; n < 4; ++n) acc[m][n] = (f32x4){0.f, 0.f, 0.f, 0.f};
#pragma unroll
    for (int kc = 0; kc < 2; ++kc)
#pragma unroll
        for (int m = 0; m < 4; ++m)
#pragma unroll
            for (int n = 0; n < 4; ++n)
                acc[m][n] = __builtin_amdgcn_mfma_f32_16x16x32_bf16(ac[m][kc], bz[n][kc], acc[m][n], 0, 0, 0);

    // per-lane code metadata
    float es_v[4][4], rc_v[4][4];
#pragma unroll
    for (int m = 0; m < 4; ++m)
#pragma unroll
        for (int r = 0; r < 4; ++r) {
            float e = e_sq[cw + m * 16 + g * 4 + r];
            es_v[m][r] = e;
            rc_v[m][r] = sqrtf(e);
        }
    float qn[4];
#pragma unroll
    for (int n = 0; n < 4; ++n) qn[n] = qtok[tok0 + n * 16 + lrow];

    // per-wave tau = min over this wave's 64 codes of (d + eps)
    float tw[4];
#pragma unroll
    for (int n = 0; n < 4; ++n) {
        float hmin = INFINITY;
#pragma unroll
        for (int m = 0; m < 4; ++m)
#pragma unroll
            for (int r = 0; r < 4; ++r) {
                float d = es_v[m][r] - 2.f * acc[m][n][r];
                hmin = fminf(hmin, d + qn[n] * rc_v[m][r]);
            }
        hmin = fminf(hmin, __shfl_xor(hmin, 16));
        hmin = fminf(hmin, __shfl_xor(hmin, 32));
        tw[n] = hmin;
    }
    if (lane < 16) {
#pragma unroll
        for (int n = 0; n < 4; ++n) tau[wid][n * 16 + lane] = tw[n];
    }
    __syncthreads();
    // block-level tau over 512 codes
    float tf[4];
#pragma unroll
    for (int n = 0; n < 4; ++n) {
        float v = tau[0][n * 16 + lrow];
#pragma unroll
        for (int w = 1; w < 8; ++w) v = fminf(v, tau[w][n * 16 + lrow]);
        tf[n] = v;
    }
    // collect candidates: lo <= tau  (true argmin provably included)
#pragma unroll
    for (int n = 0; n < 4; ++n) {
        const int tn = tok0 + n * 16 + lrow;
#pragma unroll
        for (int m = 0; m < 4; ++m)
#pragma unroll
            for (int r = 0; r < 4; ++r) {
                float d = es_v[m][r] - 2.f * acc[m][n][r];
                if (d - qn[n] * rc_v[m][r] <= tf[n]) {
                    int slot = atomicAdd(&cntT[tn], 1);
                    if (slot < CAP) cand[(size_t)tn * CAP + slot] = cw + m * 16 + g * 4 + r;
                }
            }
    }
}

// ---------------------------------------------------------------- K3b: exact f32 rescore of candidates (+ fallback)
// block 256 = 4 tokens x 64 lanes
__global__ __launch_bounds__(256) void k_vq_rescore(
    const int* __restrict__ cntT, const int* __restrict__ cand,
    const float* __restrict__ z_e, const float* __restrict__ cb,
    const float* __restrict__ e_sq,
    float* __restrict__ z_q, float* __restrict__ idx_out,
    int* __restrict__ counts, float* __restrict__ partials) {
    const int lane = threadIdx.x & 63;
    const int tg = threadIdx.x >> 6;
    const int t = blockIdx.x * 4 + tg;
    __shared__ float psum[4];

    float4 z[16];
    const float4* zr = (const float4*)(z_e + (size_t)t * EMBn);
#pragma unroll
    for (int q = 0; q < 16; ++q) z[q] = zr[q];

    const int n = cntT[t];
    float best = INFINITY;
    int bi = Kn;

    if (n > 0 && n <= CAP) {
        for (int s = lane; s < n; s += 64) {
            int c = cand[(size_t)t * CAP + s];
            const float4* cp = (const float4*)(cb + (size_t)c * EMBn);
            float a = 0.f;
#pragma unroll
            for (int q = 0; q < 16; ++q) a += dot4(z[q], cp[q]);
            float d = e_sq[c] - 2.f * a;
            if (d < best || (d == best && c < bi)) { best = d; bi = c; }
        }
    } else { // overflow (rare) or empty: exact full scan
        for (int c0 = 0; c0 < Kn; c0 += 64) {
            int c = c0 + lane;
            const float4* cp = (const float4*)(cb + (size_t)c * EMBn);
            float a = 0.f;
#pragma unroll
            for (int q = 0; q < 16; ++q) a += dot4(z[q], cp[q]);
            float d = e_sq[c] - 2.f * a;
            if (d < best) { best = d; bi = c; } // ascending c per lane
        }
    }
#pragma unroll
    for (int off = 32; off > 0; off >>= 1) {
        float od = __shfl_xor(best, off);
        int oi = __shfl_xor(bi, off);
        if (od < best || (od == best && oi < bi)) { best = od; bi = oi; }
    }

    // winner: gather z_q, loss partial, counts, index
    float cv = cb[(size_t)bi * EMBn + lane];
    z_q[(size_t)t * EMBn + lane] = cv;
    float zv = z_e[(size_t)t * EMBn + lane];
    float diff = zv - cv;
    float s = diff * diff;
#pragma unroll
    for (int off = 32; off > 0; off >>= 1) s += __shfl_xor(s, off);
    if (lane == 0) {
        psum[tg] = s;
        idx_out[t] = (float)bi;
        atomicAdd(&counts[bi], 1);
    }
    __syncthreads();
    if (threadIdx.x == 0) partials[blockIdx.x] = psum[0] + psum[1] + psum[2] + psum[3];
}

// ---------------------------------------------------------------- K4: backbone + small heads (+ h in bf16)
__global__ __launch_bounds__(256) void k_backbone(
    const float* __restrict__ z_q,
    const float* __restrict__ bb1w, const float* __restrict__ bb1b,
    const float* __restrict__ bb2w, const float* __restrict__ bb2b,
    const float* __restrict__ chw, const float* __restrict__ chb,
    const float* __restrict__ lcw, const float* __restrict__ lcb,
    float* __restrict__ h_out, unsigned short* __restrict__ hbf_out,
    float* __restrict__ cont_rec, float* __restrict__ lc_out) {
    const int tid = threadIdx.x;
    const int tok0 = blockIdx.x * 16;
    __shared__ float zq[16][68];
    __shared__ float h1[16][HIDn + 4];
    __shared__ float h2[16][HIDn + 4];
    {
        int t = tid >> 4, q = tid & 15;
        ((float4*)&zq[t][0])[q] = ((const float4*)(z_q + (size_t)(tok0 + t) * EMBn))[q];
    }
    __syncthreads();
    {
        int o = tid >> 1, half = tid & 1;
        float acc[8];
        float bv = bb1b[o];
#pragma unroll
        for (int t = 0; t < 8; ++t) acc[t] = bv;
        const float4* wr = (const float4*)(bb1w + (size_t)o * EMBn);
#pragma unroll
        for (int kk = 0; kk < 16; ++kk) {
            float4 w = wr[kk];
#pragma unroll
            for (int t = 0; t < 8; ++t) acc[t] += dot4(((const float4*)&zq[half * 8 + t][0])[kk], w);
        }
#pragma unroll
        for (int t = 0; t < 8; ++t) h1[half * 8 + t][o] = fmaxf(acc[t], 0.f);
    }
    __syncthreads();
    {
        int o = tid >> 1, half = tid & 1;
        float acc[8];
        float bv = bb2b[o];
#pragma unroll
        for (int t = 0; t < 8; ++t) acc[t] = bv;
        const float4* wr = (const float4*)(bb2w + (size_t)o * HIDn);
        for (int kk = 0; kk < 32; ++kk) {
            float4 w = wr[kk];
#pragma unroll
            for (int t = 0; t < 8; ++t) acc[t] += dot4(((const float4*)&h1[half * 8 + t][0])[kk], w);
        }
#pragma unroll
        for (int t = 0; t < 8; ++t) {
            float v = fmaxf(acc[t], 0.f);
            h2[half * 8 + t][o] = v;
            h_out[(size_t)(tok0 + half * 8 + t) * HIDn + o] = v;
            hbf_out[(size_t)(tok0 + half * 8 + t) * HIDn + o] = f2bf(v);
        }
    }
    __syncthreads();
    {
        int t = tid >> 4, o = tid & 15;
        float a = chb[o];
        const float4* wr = (const float4*)(chw + (size_t)o * HIDn);
#pragma unroll
        for (int kk = 0; kk < 32; ++kk) a += dot4(((const float4*)&h2[t][0])[kk], wr[kk]);
        cont_rec[(size_t)(tok0 + t) * CONTn + o] = a;
    }
    for (int idx = tid; idx < 16 * 32; idx += 256) {
        int t = idx >> 5, o = idx & 31;
        float a = lcb[o];
        const float4* wr = (const float4*)(lcw + (size_t)o * HIDn);
#pragma unroll
        for (int kk = 0; kk < 32; ++kk) a += dot4(((const float4*)&h2[t][0])[kk], wr[kk]);
        lc_out[(size_t)(tok0 + t) * VLCn + o] = a;
    }
}

// ---------------------------------------------------------------- K5: sp_logits via bf16 MFMA, direct-from-L2 frags
__global__ __launch_bounds__(256, 3) void k_sp_mfma(
    const unsigned short* __restrict__ hbf, const unsigned short* __restrict__ wbf,
    const float* __restrict__ bias, float* __restrict__ out) {
    const int tid = threadIdx.x;
    const int lane = tid & 63;
    const int wid = tid >> 6;
    const int tok_w = blockIdx.y * 128 + (wid & 1) * 64;
    const int v_w = blockIdx.x * 128 + (wid >> 1) * 64;

    const int lrow = lane & 15;
    const int lk = (lane >> 4) * 8;

    const unsigned short* ha = hbf + (size_t)(tok_w + lrow) * HIDn + lk;
    const unsigned short* wa = wbf + (size_t)(v_w + lrow) * HIDn + lk;

    f32x4 acc[4][4];
#pragma unroll
    for (int m = 0; m < 4; ++m)
#pragma unroll
        for (int n = 0; n < 4; ++n) acc[m][n] = (f32x4){0.f, 0.f, 0.f, 0.f};

#pragma unroll
    for (int ks = 0; ks < 4; ++ks) {
        const int kk = ks * 32;
        short8v a[4], b[4];
#pragma unroll
        for (int m = 0; m < 4; ++m)
            a[m] = *(const short8v*)(ha + (size_t)m * 16 * HIDn + kk);
#pragma unroll
        for (int n = 0; n < 4; ++n)
            b[n] = *(const short8v*)(wa + (size_t)n * 16 * HIDn + kk);
#pragma unroll
        for (int m = 0; m < 4; ++m)
#pragma unroll
            for (int n = 0; n < 4; ++n)
                acc[m][n] = __builtin_amdgcn_mfma_f32_16x16x32_bf16(a[m], b[n], acc[m][n], 0, 0, 0);
    }

    const int r0 = (lane >> 4) * 4;
#pragma unroll
    for (int n = 0; n < 4; ++n) {
        const int col = v_w + n * 16 + lrow;
        if (col < VSPn) {
            const float bv = bias[col];
#pragma unroll
            for (int m = 0; m < 4; ++m) {
                const int row = tok_w + m * 16 + r0;
#pragma unroll
                for (int r = 0; r < 4; ++r)
                    out[(size_t)(row + r) * VSPn + col] = acc[m][n][r] + bv;
            }
        }
    }
}

// ---------------------------------------------------------------- K6: canopy head on h[:, -1, :]
__global__ __launch_bounds__(128) void k_canopy(const float* __restrict__ h,
                                                const float* __restrict__ w1,
                                                const float* __restrict__ b1,
                                                const float* __restrict__ w2,
                                                const float* __restrict__ b2,
                                                float* __restrict__ can) {
    int b = blockIdx.x, o = threadIdx.x;
    __shared__ float r[128];
    const float4* hr = (const float4*)(h + (size_t)(b * Tn + Tn - 1) * HIDn);
    const float4* wr = (const float4*)(w1 + (size_t)o * HIDn);
    float a = b1[o];
#pragma unroll
    for (int kk = 0; kk < 32; ++kk) a += dot4(hr[kk], wr[kk]);
    r[o] = fmaxf(a, 0.f) * w2[o];
    __syncthreads();
    for (int s = 64; s > 0; s >>= 1) {
        if (o < s) r[o] += r[o + s];
        __syncthreads();
    }
    if (o == 0) can[b] = r[0] + b2[0];
}

// ---------------------------------------------------------------- K7: loss + perplexity
__global__ __launch_bounds__(256) void k_finalize(const float* __restrict__ partials,
                                                  const int* __restrict__ counts,
                                                  float* __restrict__ out_loss,
                                                  float* __restrict__ out_ppl) {
    const int tid = threadIdx.x;
    __shared__ float red[256];
    float ps = 0.f;
#pragma unroll
    for (int j = 0; j < (BTn / 4) / 256; ++j) ps += partials[tid * ((BTn / 4) / 256) + j];
    red[tid] = ps;
    __syncthreads();
    for (int s = 128; s > 0; s >>= 1) {
        if (tid < s) red[tid] += red[tid + s];
        __syncthreads();
    }
    float total = red[0];
    __syncthreads();
    float e = 0.f;
    for (int i = tid; i < Kn; i += 256) {
        float p = (float)counts[i] * (1.0f / BTn);
        e += p * logf(p + 1e-12f);
    }
    red[tid] = e;
    __syncthreads();
    for (int s = 128; s > 0; s >>= 1) {
        if (tid < s) red[tid] += red[tid + s];
        __syncthreads();
    }
    if (tid == 0) {
        out_loss[0] = 1.25f * total / (float)((size_t)BTn * EMBn);
        out_ppl[0] = expf(-red[0]);
    }
}

// ----------------------------------------------------------------
extern "C" void kernel_launch(void* const* d_in, const int* in_sizes, int n_in,
                              void* d_out, int out_size, void* d_ws, size_t ws_size,
                              hipStream_t stream) {
    const float* cont = (const float*)d_in[0];
    const float* naip = (const float*)d_in[1];
    const int* cat = (const int*)d_in[2];
    const float* emb_sp = (const float*)d_in[3];
    const float* emb_lc = (const float*)d_in[4];
    const float* conv_w = (const float*)d_in[5];
    const float* conv_b = (const float*)d_in[6];
    const float* npw = (const float*)d_in[7];
    const float* npb = (const float*)d_in[8];
    const float* cpw = (const float*)d_in[9];
    const float* cpb = (const float*)d_in[10];
    const float* caw = (const float*)d_in[11];
    const float* cab = (const float*)d_in[12];
    const float* f1w = (const float*)d_in[13];
    const float* f1b = (const float*)d_in[14];
    const float* f2w = (const float*)d_in[15];
    const float* f2b = (const float*)d_in[16];
    const float* cb = (const float*)d_in[17];
    const float* bb1w = (const float*)d_in[18];
    const float* bb1b = (const float*)d_in[19];
    const float* bb2w = (const float*)d_in[20];
    const float* bb2b = (const float*)d_in[21];
    const float* chw = (const float*)d_in[22];
    const float* chb = (const float*)d_in[23];
    const float* spw = (const float*)d_in[24];
    const float* spb = (const float*)d_in[25];
    const float* lcw = (const float*)d_in[26];
    const float* lcb = (const float*)d_in[27];
    const float* c1w = (const float*)d_in[28];
    const float* c1b = (const float*)d_in[29];
    const float* c2w = (const float*)d_in[30];
    const float* c2b = (const float*)d_in[31];

    float* out = (float*)d_out;
    float* ws = (float*)d_ws;
    float* naip2 = ws + WS_NAIP2;
    float* z_e = ws + WS_ZE;
    float* z_q = ws + WS_ZQ;
    float* h = ws + WS_H;
    float* e_sq = ws + WS_ESQ;
    float* parts = ws + WS_PART;
    int* counts = (int*)(ws + WS_CNTK);
    int* cntT = (int*)(ws + WS_CNTT);
    float* qtok = ws + WS_Q;
    int* cand = (int*)(ws + WS_CAND);
    unsigned short* zbf = (unsigned short*)(ws + WS_ZBF);
    unsigned short* cbbf = (unsigned short*)(ws + WS_CBBF);
    unsigned short* hbf = (unsigned short*)(ws + WS_HBF);
    unsigned short* wbf = (unsigned short*)(ws + WS_WBF);

    k_esq_zero<<<dim3(Kn / 256), dim3(256), 0, stream>>>(cb, e_sq, counts, cbbf);
    k_wcast<<<dim3(VSP_PAD * HIDn / 4 / 256), dim3(256), 0, stream>>>(spw, wbf);
    k_naip<<<dim3(Bn), dim3(128), 0, stream>>>(naip, conv_w, conv_b, npw, npb, naip2);
    k_ze<<<dim3(BTn / 16), dim3(256), 0, stream>>>(cont, cat, emb_sp, emb_lc, cpw, cpb, caw, cab,
                                                   f1w, f1b, f2w, f2b, naip2, z_e);
    k_zprep<<<dim3(BTn / 4), dim3(256), 0, stream>>>(z_e, zbf, qtok, cntT);
    k_vq_score<<<dim3(Kn / 512, BTn / 64), dim3(512), 0, stream>>>(zbf, cbbf, e_sq, qtok, cntT, cand);
    k_vq_rescore<<<dim3(BTn / 4), dim3(256), 0, stream>>>(cntT, cand, z_e, cb, e_sq, z_q,
                                                          out + O_IDX, counts, parts);
    k_backbone<<<dim3(BTn / 16), dim3(256), 0, stream>>>(z_q, bb1w, bb1b, bb2w, bb2b, chw, chb,
                                                         lcw, lcb, h, hbf, out + O_CONT, out + O_LC);
    k_sp_mfma<<<dim3(VSP_PAD / 128, BTn / 128), dim3(256), 0, stream>>>(hbf, wbf, spb, out + O_SP);
    k_canopy<<<dim3(Bn), dim3(128), 0, stream>>>(h, c1w, c1b, c2w, c2b, out + O_CAN);
    k_finalize<<<dim3(1), dim3(256), 0, stream>>>(parts, counts, out + O_LOSS, out + O_PPL);
}

// Round 7
// 328.692 us; speedup vs baseline: 2.3209x; 1.2855x over previous
//
#include <hip/hip_runtime.h>
#include <cmath>

namespace {
constexpr int Bn = 128, Tn = 128, BTn = Bn * Tn;
constexpr int CONTn = 16, HIDn = 128, EMBn = 64;
constexpr int Kn = 8192, CEn = 6, VSPn = 2000, VLCn = 32, FINn = 3 * HIDn;
constexpr int VSP_PAD = 2048;             // padded vocab for MFMA tiles
constexpr int CAP = 64;                   // max stored VQ candidates per token
constexpr float EPSC = 0.02f;             // rigorous bf16 interval coeff (2^-6 * 1.28; bf16 mantissa=7 bits)
constexpr int VQ_Q = 4;                   // K quarters
constexpr int KQ = Kn / VQ_Q;             // 2048 codes per quarter

// ---- workspace layout (float units) ----
constexpr size_t WS_NAIP2 = 0;                               // B*HID
constexpr size_t WS_ZE    = WS_NAIP2 + (size_t)Bn * HIDn;    // BT*EMB
constexpr size_t WS_ZQ    = WS_ZE + (size_t)BTn * EMBn;      // BT*EMB
constexpr size_t WS_H     = WS_ZQ + (size_t)BTn * EMBn;      // BT*HID
constexpr size_t WS_ESQ   = WS_H + (size_t)BTn * HIDn;       // K
constexpr size_t WS_PART  = WS_ESQ + Kn;                     // BT/4 partial loss sums
constexpr size_t WS_CNTK  = WS_PART + BTn / 4;               // K ints (code counts)
constexpr size_t WS_CNTT  = WS_CNTK + Kn;                    // BT ints (candidate counts)
constexpr size_t WS_Q     = WS_CNTT + BTn;                   // BT floats (eps per token)
constexpr size_t WS_CAND  = WS_Q + BTn;                      // BT*CAP ints
constexpr size_t WS_ZBF   = WS_CAND + (size_t)BTn * CAP;     // BT*EMB ushort
constexpr size_t WS_CBBF  = WS_ZBF + (size_t)BTn * EMBn / 2; // K*EMB ushort
constexpr size_t WS_HBF   = WS_CBBF + (size_t)Kn * EMBn / 2; // BT*HID ushort
constexpr size_t WS_WBF   = WS_HBF + (size_t)BTn * HIDn / 2; // VSP_PAD*HID ushort
constexpr size_t WS_ESRC  = WS_WBF + (size_t)VSP_PAD * HIDn / 2; // K float2 {e_sq, sqrt(e_sq)}

// ---- output layout (float units) ----
constexpr size_t O_CONT = 0;
constexpr size_t O_SP   = O_CONT + (size_t)BTn * CONTn;
constexpr size_t O_LC   = O_SP + (size_t)BTn * VSPn;
constexpr size_t O_CAN  = O_LC + (size_t)BTn * VLCn;
constexpr size_t O_IDX  = O_CAN + Bn;
constexpr size_t O_LOSS = O_IDX + BTn;
constexpr size_t O_PPL  = O_LOSS + 1;
} // namespace

typedef __attribute__((ext_vector_type(8))) short short8v;  // 8 bf16 = 4 VGPR
typedef __attribute__((ext_vector_type(4))) float f32x4;

__device__ __forceinline__ float nan0(float v) {
    return __builtin_isfinite(v) ? v : 0.0f;
}
__device__ __forceinline__ float dot4(float4 a, float4 b) {
    return a.x * b.x + a.y * b.y + a.z * b.z + a.w * b.w;
}
__device__ __forceinline__ unsigned short f2bf(float f) { // RNE, finite-only
    union { float f; unsigned u; } v{f};
    unsigned r = v.u + 0x7FFFu + ((v.u >> 16) & 1u);
    return (unsigned short)(r >> 16);
}

// ---------------------------------------------------------------- K0: zero code counts + e_sq/esrc + bf16 codebook
__global__ __launch_bounds__(256) void k_esq_zero(const float* __restrict__ cb,
                                                  float* __restrict__ e_sq,
                                                  float2* __restrict__ esrc,
                                                  int* __restrict__ counts,
                                                  unsigned short* __restrict__ cbbf) {
    int i = blockIdx.x * 256 + threadIdx.x;
    if (i < Kn) {
        counts[i] = 0;
        const float4* r = (const float4*)(cb + (size_t)i * EMBn);
        float s = 0.f;
#pragma unroll
        for (int j = 0; j < 16; ++j) {
            float4 v = r[j];
            s += dot4(v, v);
            unsigned short u[4] = {f2bf(v.x), f2bf(v.y), f2bf(v.z), f2bf(v.w)};
            *(uint2*)(cbbf + (size_t)i * EMBn + j * 4) = *(const uint2*)u;
        }
        e_sq[i] = s;
        esrc[i] = make_float2(s, sqrtf(s));
    }
}

// ---------------------------------------------------------------- K0b: sp_head_w -> bf16, padded to 2048 rows
__global__ __launch_bounds__(256) void k_wcast(const float* __restrict__ w,
                                               unsigned short* __restrict__ wbf) {
    int i = blockIdx.x * 256 + threadIdx.x;      // float4 index; 32 per row
    int v = i >> 5;
    unsigned short u[4] = {0, 0, 0, 0};
    if (v < VSPn) {
        float4 x = ((const float4*)w)[i];
        u[0] = f2bf(x.x); u[1] = f2bf(x.y); u[2] = f2bf(x.z); u[3] = f2bf(x.w);
    }
    *(uint2*)(wbf + (size_t)i * 4) = *(const uint2*)u;
}

// ---------------------------------------------------------------- K1: naip conv + proj -> naip2 (B x HID)
__global__ __launch_bounds__(128) void k_naip(const float* __restrict__ naip,
                                              const float* __restrict__ conv_w,
                                              const float* __restrict__ conv_b,
                                              const float* __restrict__ pw,
                                              const float* __restrict__ pb,
                                              float* __restrict__ naip2) {
    int b = blockIdx.x, o = threadIdx.x;
    __shared__ float feat[HIDn];
    float acc = conv_b[o];
#pragma unroll
    for (int i = 0; i < 9; ++i) acc += nan0(naip[b * 9 + i]) * conv_w[o * 9 + i];
    feat[o] = fmaxf(acc, 0.f);
    __syncthreads();
    float a2 = pb[o];
    const float4* wr = (const float4*)(pw + (size_t)o * HIDn);
    const float4* fr = (const float4*)feat;
#pragma unroll
    for (int j = 0; j < 32; ++j) a2 += dot4(fr[j], wr[j]);
    naip2[(size_t)b * HIDn + o] = a2;
}

// ---------------------------------------------------------------- K2: fused inputs -> z_e (BT x EMB)
__global__ __launch_bounds__(256) void k_ze(
    const float* __restrict__ cont, const int* __restrict__ cat,
    const float* __restrict__ emb_sp, const float* __restrict__ emb_lc,
    const float* __restrict__ cpw, const float* __restrict__ cpb,
    const float* __restrict__ caw, const float* __restrict__ cab,
    const float* __restrict__ f1w, const float* __restrict__ f1b,
    const float* __restrict__ f2w, const float* __restrict__ f2b,
    const float* __restrict__ naip2, float* __restrict__ z_e) {
    const int tok0 = blockIdx.x * 16;
    const int tid = threadIdx.x;
    __shared__ float fused[16][FINn + 4];
    __shared__ float h1[16][HIDn + 4];

    for (int idx = tid; idx < 16 * HIDn; idx += 256) {
        int t = idx >> 7, j = idx & 127;
        int b = (tok0 + t) / Tn;
        fused[t][j] = naip2[(size_t)b * HIDn + j];
    }
    for (int idx = tid; idx < 16 * HIDn; idx += 256) {
        int t = idx >> 7, o = idx & 127;
        int tok = tok0 + t;
        const float4* cp = (const float4*)(cont + (size_t)tok * CONTn);
        const float4* wr = (const float4*)(cpw + (size_t)o * CONTn);
        float a = cpb[o];
#pragma unroll
        for (int q = 0; q < 4; ++q) {
            float4 c4 = cp[q], w4 = wr[q];
            a += nan0(c4.x) * w4.x + nan0(c4.y) * w4.y + nan0(c4.z) * w4.z + nan0(c4.w) * w4.w;
        }
        fused[t][HIDn + o] = a;
    }
    for (int idx = tid; idx < 16 * HIDn; idx += 256) {
        int t = idx >> 7, o = idx & 127;
        int tok = tok0 + t;
        int c0 = cat[tok * 2], c1 = cat[tok * 2 + 1];
        const float* e0 = emb_sp + (size_t)c0 * CEn;
        const float* e1 = emb_lc + (size_t)c1 * CEn;
        const float* wr = caw + (size_t)o * (2 * CEn);
        float a = cab[o];
#pragma unroll
        for (int i = 0; i < CEn; ++i) a += e0[i] * wr[i];
#pragma unroll
        for (int i = 0; i < CEn; ++i) a += e1[i] * wr[CEn + i];
        fused[t][2 * HIDn + o] = a;
    }
    __syncthreads();
    {
        int o = tid >> 1, half = tid & 1;
        float acc[8];
        float bv = f1b[o];
#pragma unroll
        for (int t = 0; t < 8; ++t) acc[t] = bv;
        const float4* wr = (const float4*)(f1w + (size_t)o * FINn);
        for (int kk = 0; kk < FINn / 4; ++kk) {
            float4 w = wr[kk];
#pragma unroll
            for (int t = 0; t < 8; ++t) {
                float4 f = ((const float4*)&fused[half * 8 + t][0])[kk];
                acc[t] += dot4(f, w);
            }
        }
#pragma unroll
        for (int t = 0; t < 8; ++t) h1[half * 8 + t][o] = fmaxf(acc[t], 0.f);
    }
    __syncthreads();
    {
        int o = tid & 63, tg = tid >> 6;
        float acc[4];
        float bv = f2b[o];
#pragma unroll
        for (int t = 0; t < 4; ++t) acc[t] = bv;
        const float4* wr = (const float4*)(f2w + (size_t)o * HIDn);
        for (int kk = 0; kk < HIDn / 4; ++kk) {
            float4 w = wr[kk];
#pragma unroll
            for (int t = 0; t < 4; ++t) {
                float4 f = ((const float4*)&h1[tg * 4 + t][0])[kk];
                acc[t] += dot4(f, w);
            }
        }
#pragma unroll
        for (int t = 0; t < 4; ++t) z_e[(size_t)(tok0 + tg * 4 + t) * EMBn + o] = acc[t];
    }
}

// ---------------------------------------------------------------- K3p: z -> bf16, per-token eps, zero cand counts
__global__ __launch_bounds__(256) void k_zprep(const float* __restrict__ z_e,
                                               unsigned short* __restrict__ zbf,
                                               float* __restrict__ qtok,
                                               int* __restrict__ cntT) {
    const int lane = threadIdx.x & 63;
    const int tg = threadIdx.x >> 6;
    const int t = blockIdx.x * 4 + tg;
    float zv = z_e[(size_t)t * EMBn + lane];
    zbf[(size_t)t * EMBn + lane] = f2bf(zv);
    float s = zv * zv;
#pragma unroll
    for (int off = 32; off > 0; off >>= 1) s += __shfl_xor(s, off);
    if (lane == 0) {
        qtok[t] = EPSC * sqrtf(s);
        cntT[t] = 0;
    }
}

// ---------------------------------------------------------------- K3a: VQ scoring, two-pass (tau then collect)
// grid (VQ_Q, BTn/64); block 256 = 4 waves. Wave tile per step: 32 codes x 64 tokens.
// Pass A: running per-lane min(d + eps_c) -> exact quarter tau (one reduce).
// Pass B: identical MFMA recompute; collect d - eps_c <= tau (provably contains argmin).
__global__ __launch_bounds__(256, 3) void k_vq_score2(
    const unsigned short* __restrict__ zbf, const unsigned short* __restrict__ cbbf,
    const float2* __restrict__ esrc, const float* __restrict__ qtok,
    int* __restrict__ cntT, int* __restrict__ cand) {
    const int tid = threadIdx.x;
    const int lane = tid & 63;
    const int wid = tid >> 6;          // 0..3
    const int lrow = lane & 15;
    const int g = lane >> 4;           // 0..3
    const int tok0 = blockIdx.y * 64;
    const int cq = blockIdx.x * KQ;

    __shared__ float tau[4][64];

    // persistent z fragments (B operand; N = tokens)
    short8v bz[4][2];
#pragma unroll
    for (int n = 0; n < 4; ++n)
#pragma unroll
        for (int kc = 0; kc < 2; ++kc)
            bz[n][kc] = *(const short8v*)(zbf + (size_t)(tok0 + n * 16 + lrow) * EMBn + kc * 32 + g * 8);
    float qn[4];
#pragma unroll
    for (int n = 0; n < 4; ++n) qn[n] = qtok[tok0 + n * 16 + lrow];

    float tA[4] = {INFINITY, INFINITY, INFINITY, INFINITY};

    // ---- pass A
    for (int step = 0; step < KQ / 128; ++step) {
        const int c0 = cq + step * 128 + wid * 32;
        short8v ac[2][2];
#pragma unroll
        for (int m = 0; m < 2; ++m)
#pragma unroll
            for (int kc = 0; kc < 2; ++kc)
                ac[m][kc] = *(const short8v*)(cbbf + (size_t)(c0 + m * 16 + lrow) * EMBn + kc * 32 + g * 8);
        float2 er[2][4];
#pragma unroll
        for (int m = 0; m < 2; ++m)
#pragma unroll
            for (int r = 0; r < 4; ++r) er[m][r] = esrc[c0 + m * 16 + g * 4 + r];
        f32x4 acc[2][4];
#pragma unroll
        for (int m = 0; m < 2; ++m)
#pragma unroll
            for (int n = 0; n < 4; ++n) acc[m][n] = (f32x4){0.f, 0.f, 0.f, 0.f};
#pragma unroll
        for (int kc = 0; kc < 2; ++kc)
#pragma unroll
            for (int m = 0; m < 2; ++m)
#pragma unroll
                for (int n = 0; n < 4; ++n)
                    acc[m][n] = __builtin_amdgcn_mfma_f32_16x16x32_bf16(ac[m][kc], bz[n][kc], acc[m][n], 0, 0, 0);
#pragma unroll
        for (int n = 0; n < 4; ++n)
#pragma unroll
            for (int m = 0; m < 2; ++m)
#pragma unroll
                for (int r = 0; r < 4; ++r) {
                    float d = fmaf(-2.f, acc[m][n][r], er[m][r].x);
                    float hi = fmaf(qn[n], er[m][r].y, d);
                    tA[n] = fminf(tA[n], hi);
                }
    }
#pragma unroll
    for (int n = 0; n < 4; ++n) {
        tA[n] = fminf(tA[n], __shfl_xor(tA[n], 16));
        tA[n] = fminf(tA[n], __shfl_xor(tA[n], 32));
    }
    if (lane < 16) {
#pragma unroll
        for (int n = 0; n < 4; ++n) tau[wid][n * 16 + lane] = tA[n];
    }
    __syncthreads();
    float tf[4];
#pragma unroll
    for (int n = 0; n < 4; ++n)
        tf[n] = fminf(fminf(tau[0][n * 16 + lrow], tau[1][n * 16 + lrow]),
                      fminf(tau[2][n * 16 + lrow], tau[3][n * 16 + lrow]));

    // ---- pass B (bitwise-identical d recompute)
    for (int step = 0; step < KQ / 128; ++step) {
        const int c0 = cq + step * 128 + wid * 32;
        short8v ac[2][2];
#pragma unroll
        for (int m = 0; m < 2; ++m)
#pragma unroll
            for (int kc = 0; kc < 2; ++kc)
                ac[m][kc] = *(const short8v*)(cbbf + (size_t)(c0 + m * 16 + lrow) * EMBn + kc * 32 + g * 8);
        float2 er[2][4];
#pragma unroll
        for (int m = 0; m < 2; ++m)
#pragma unroll
            for (int r = 0; r < 4; ++r) er[m][r] = esrc[c0 + m * 16 + g * 4 + r];
        f32x4 acc[2][4];
#pragma unroll
        for (int m = 0; m < 2; ++m)
#pragma unroll
            for (int n = 0; n < 4; ++n) acc[m][n] = (f32x4){0.f, 0.f, 0.f, 0.f};
#pragma unroll
        for (int kc = 0; kc < 2; ++kc)
#pragma unroll
            for (int m = 0; m < 2; ++m)
#pragma unroll
                for (int n = 0; n < 4; ++n)
                    acc[m][n] = __builtin_amdgcn_mfma_f32_16x16x32_bf16(ac[m][kc], bz[n][kc], acc[m][n], 0, 0, 0);
#pragma unroll
        for (int n = 0; n < 4; ++n)
#pragma unroll
            for (int m = 0; m < 2; ++m)
#pragma unroll
                for (int r = 0; r < 4; ++r) {
                    float d = fmaf(-2.f, acc[m][n][r], er[m][r].x);
                    float lo = fmaf(-qn[n], er[m][r].y, d);
                    if (lo <= tf[n]) {
                        const int tn = tok0 + n * 16 + lrow;
                        int slot = atomicAdd(&cntT[tn], 1);
                        if (slot < CAP) cand[(size_t)tn * CAP + slot] = c0 + m * 16 + g * 4 + r;
                    }
                }
    }
}

// ---------------------------------------------------------------- K3b: exact f32 rescore of candidates (+ fallback)
__global__ __launch_bounds__(256) void k_vq_rescore(
    const int* __restrict__ cntT, const int* __restrict__ cand,
    const float* __restrict__ z_e, const float* __restrict__ cb,
    const float* __restrict__ e_sq,
    float* __restrict__ z_q, float* __restrict__ idx_out,
    int* __restrict__ counts, float* __restrict__ partials) {
    const int lane = threadIdx.x & 63;
    const int tg = threadIdx.x >> 6;
    const int t = blockIdx.x * 4 + tg;
    __shared__ float psum[4];

    float4 z[16];
    const float4* zr = (const float4*)(z_e + (size_t)t * EMBn);
#pragma unroll
    for (int q = 0; q < 16; ++q) z[q] = zr[q];

    const int n = cntT[t];
    float best = INFINITY;
    int bi = Kn;

    if (n > 0 && n <= CAP) {
        for (int s = lane; s < n; s += 64) {
            int c = cand[(size_t)t * CAP + s];
            const float4* cp = (const float4*)(cb + (size_t)c * EMBn);
            float a = 0.f;
#pragma unroll
            for (int q = 0; q < 16; ++q) a += dot4(z[q], cp[q]);
            float d = e_sq[c] - 2.f * a;
            if (d < best || (d == best && c < bi)) { best = d; bi = c; }
        }
    } else { // overflow (pathological) or empty: exact full scan
        for (int c0 = 0; c0 < Kn; c0 += 64) {
            int c = c0 + lane;
            const float4* cp = (const float4*)(cb + (size_t)c * EMBn);
            float a = 0.f;
#pragma unroll
            for (int q = 0; q < 16; ++q) a += dot4(z[q], cp[q]);
            float d = e_sq[c] - 2.f * a;
            if (d < best) { best = d; bi = c; } // ascending c per lane
        }
    }
#pragma unroll
    for (int off = 32; off > 0; off >>= 1) {
        float od = __shfl_xor(best, off);
        int oi = __shfl_xor(bi, off);
        if (od < best || (od == best && oi < bi)) { best = od; bi = oi; }
    }

    float cv = cb[(size_t)bi * EMBn + lane];
    z_q[(size_t)t * EMBn + lane] = cv;
    float zv = z_e[(size_t)t * EMBn + lane];
    float diff = zv - cv;
    float s = diff * diff;
#pragma unroll
    for (int off = 32; off > 0; off >>= 1) s += __shfl_xor(s, off);
    if (lane == 0) {
        psum[tg] = s;
        idx_out[t] = (float)bi;
        atomicAdd(&counts[bi], 1);
    }
    __syncthreads();
    if (threadIdx.x == 0) partials[blockIdx.x] = psum[0] + psum[1] + psum[2] + psum[3];
}

// ---------------------------------------------------------------- K4: backbone + small heads (+ h in bf16)
__global__ __launch_bounds__(256) void k_backbone(
    const float* __restrict__ z_q,
    const float* __restrict__ bb1w, const float* __restrict__ bb1b,
    const float* __restrict__ bb2w, const float* __restrict__ bb2b,
    const float* __restrict__ chw, const float* __restrict__ chb,
    const float* __restrict__ lcw, const float* __restrict__ lcb,
    float* __restrict__ h_out, unsigned short* __restrict__ hbf_out,
    float* __restrict__ cont_rec, float* __restrict__ lc_out) {
    const int tid = threadIdx.x;
    const int tok0 = blockIdx.x * 16;
    __shared__ float zq[16][68];
    __shared__ float h1[16][HIDn + 4];
    __shared__ float h2[16][HIDn + 4];
    {
        int t = tid >> 4, q = tid & 15;
        ((float4*)&zq[t][0])[q] = ((const float4*)(z_q + (size_t)(tok0 + t) * EMBn))[q];
    }
    __syncthreads();
    {
        int o = tid >> 1, half = tid & 1;
        float acc[8];
        float bv = bb1b[o];
#pragma unroll
        for (int t = 0; t < 8; ++t) acc[t] = bv;
        const float4* wr = (const float4*)(bb1w + (size_t)o * EMBn);
#pragma unroll
        for (int kk = 0; kk < 16; ++kk) {
            float4 w = wr[kk];
#pragma unroll
            for (int t = 0; t < 8; ++t) acc[t] += dot4(((const float4*)&zq[half * 8 + t][0])[kk], w);
        }
#pragma unroll
        for (int t = 0; t < 8; ++t) h1[half * 8 + t][o] = fmaxf(acc[t], 0.f);
    }
    __syncthreads();
    {
        int o = tid >> 1, half = tid & 1;
        float acc[8];
        float bv = bb2b[o];
#pragma unroll
        for (int t = 0; t < 8; ++t) acc[t] = bv;
        const float4* wr = (const float4*)(bb2w + (size_t)o * HIDn);
        for (int kk = 0; kk < 32; ++kk) {
            float4 w = wr[kk];
#pragma unroll
            for (int t = 0; t < 8; ++t) acc[t] += dot4(((const float4*)&h1[half * 8 + t][0])[kk], w);
        }
#pragma unroll
        for (int t = 0; t < 8; ++t) {
            float v = fmaxf(acc[t], 0.f);
            h2[half * 8 + t][o] = v;
            h_out[(size_t)(tok0 + half * 8 + t) * HIDn + o] = v;
            hbf_out[(size_t)(tok0 + half * 8 + t) * HIDn + o] = f2bf(v);
        }
    }
    __syncthreads();
    {
        int t = tid >> 4, o = tid & 15;
        float a = chb[o];
        const float4* wr = (const float4*)(chw + (size_t)o * HIDn);
#pragma unroll
        for (int kk = 0; kk < 32; ++kk) a += dot4(((const float4*)&h2[t][0])[kk], wr[kk]);
        cont_rec[(size_t)(tok0 + t) * CONTn + o] = a;
    }
    for (int idx = tid; idx < 16 * 32; idx += 256) {
        int t = idx >> 5, o = idx & 31;
        float a = lcb[o];
        const float4* wr = (const float4*)(lcw + (size_t)o * HIDn);
#pragma unroll
        for (int kk = 0; kk < 32; ++kk) a += dot4(((const float4*)&h2[t][0])[kk], wr[kk]);
        lc_out[(size_t)(tok0 + t) * VLCn + o] = a;
    }
}

// ---------------------------------------------------------------- K5: sp_logits via bf16 MFMA, direct-from-L2 frags
__global__ __launch_bounds__(256, 3) void k_sp_mfma(
    const unsigned short* __restrict__ hbf, const unsigned short* __restrict__ wbf,
    const float* __restrict__ bias, float* __restrict__ out) {
    const int tid = threadIdx.x;
    const int lane = tid & 63;
    const int wid = tid >> 6;
    const int tok_w = blockIdx.y * 128 + (wid & 1) * 64;
    const int v_w = blockIdx.x * 128 + (wid >> 1) * 64;

    const int lrow = lane & 15;
    const int lk = (lane >> 4) * 8;

    const unsigned short* ha = hbf + (size_t)(tok_w + lrow) * HIDn + lk;
    const unsigned short* wa = wbf + (size_t)(v_w + lrow) * HIDn + lk;

    f32x4 acc[4][4];
#pragma unroll
    for (int m = 0; m < 4; ++m)
#pragma unroll
        for (int n = 0; n < 4; ++n) acc[m][n] = (f32x4){0.f, 0.f, 0.f, 0.f};

#pragma unroll
    for (int ks = 0; ks < 4; ++ks) {
        const int kk = ks * 32;
        short8v a[4], b[4];
#pragma unroll
        for (int m = 0; m < 4; ++m)
            a[m] = *(const short8v*)(ha + (size_t)m * 16 * HIDn + kk);
#pragma unroll
        for (int n = 0; n < 4; ++n)
            b[n] = *(const short8v*)(wa + (size_t)n * 16 * HIDn + kk);
#pragma unroll
        for (int m = 0; m < 4; ++m)
#pragma unroll
            for (int n = 0; n < 4; ++n)
                acc[m][n] = __builtin_amdgcn_mfma_f32_16x16x32_bf16(a[m], b[n], acc[m][n], 0, 0, 0);
    }

    const int r0 = (lane >> 4) * 4;
#pragma unroll
    for (int n = 0; n < 4; ++n) {
        const int col = v_w + n * 16 + lrow;
        if (col < VSPn) {
            const float bv = bias[col];
#pragma unroll
            for (int m = 0; m < 4; ++m) {
                const int row = tok_w + m * 16 + r0;
#pragma unroll
                for (int r = 0; r < 4; ++r)
                    out[(size_t)(row + r) * VSPn + col] = acc[m][n][r] + bv;
            }
        }
    }
}

// ---------------------------------------------------------------- K6: canopy head on h[:, -1, :]
__global__ __launch_bounds__(128) void k_canopy(const float* __restrict__ h,
                                                const float* __restrict__ w1,
                                                const float* __restrict__ b1,
                                                const float* __restrict__ w2,
                                                const float* __restrict__ b2,
                                                float* __restrict__ can) {
    int b = blockIdx.x, o = threadIdx.x;
    __shared__ float r[128];
    const float4* hr = (const float4*)(h + (size_t)(b * Tn + Tn - 1) * HIDn);
    const float4* wr = (const float4*)(w1 + (size_t)o * HIDn);
    float a = b1[o];
#pragma unroll
    for (int kk = 0; kk < 32; ++kk) a += dot4(hr[kk], wr[kk]);
    r[o] = fmaxf(a, 0.f) * w2[o];
    __syncthreads();
    for (int s = 64; s > 0; s >>= 1) {
        if (o < s) r[o] += r[o + s];
        __syncthreads();
    }
    if (o == 0) can[b] = r[0] + b2[0];
}

// ---------------------------------------------------------------- K7: loss + perplexity
__global__ __launch_bounds__(256) void k_finalize(const float* __restrict__ partials,
                                                  const int* __restrict__ counts,
                                                  float* __restrict__ out_loss,
                                                  float* __restrict__ out_ppl) {
    const int tid = threadIdx.x;
    __shared__ float red[256];
    float ps = 0.f;
#pragma unroll
    for (int j = 0; j < (BTn / 4) / 256; ++j) ps += partials[tid * ((BTn / 4) / 256) + j];
    red[tid] = ps;
    __syncthreads();
    for (int s = 128; s > 0; s >>= 1) {
        if (tid < s) red[tid] += red[tid + s];
        __syncthreads();
    }
    float total = red[0];
    __syncthreads();
    float e = 0.f;
    for (int i = tid; i < Kn; i += 256) {
        float p = (float)counts[i] * (1.0f / BTn);
        e += p * logf(p + 1e-12f);
    }
    red[tid] = e;
    __syncthreads();
    for (int s = 128; s > 0; s >>= 1) {
        if (tid < s) red[tid] += red[tid + s];
        __syncthreads();
    }
    if (tid == 0) {
        out_loss[0] = 1.25f * total / (float)((size_t)BTn * EMBn);
        out_ppl[0] = expf(-red[0]);
    }
}

// ----------------------------------------------------------------
extern "C" void kernel_launch(void* const* d_in, const int* in_sizes, int n_in,
                              void* d_out, int out_size, void* d_ws, size_t ws_size,
                              hipStream_t stream) {
    const float* cont = (const float*)d_in[0];
    const float* naip = (const float*)d_in[1];
    const int* cat = (const int*)d_in[2];
    const float* emb_sp = (const float*)d_in[3];
    const float* emb_lc = (const float*)d_in[4];
    const float* conv_w = (const float*)d_in[5];
    const float* conv_b = (const float*)d_in[6];
    const float* npw = (const float*)d_in[7];
    const float* npb = (const float*)d_in[8];
    const float* cpw = (const float*)d_in[9];
    const float* cpb = (const float*)d_in[10];
    const float* caw = (const float*)d_in[11];
    const float* cab = (const float*)d_in[12];
    const float* f1w = (const float*)d_in[13];
    const float* f1b = (const float*)d_in[14];
    const float* f2w = (const float*)d_in[15];
    const float* f2b = (const float*)d_in[16];
    const float* cb = (const float*)d_in[17];
    const float* bb1w = (const float*)d_in[18];
    const float* bb1b = (const float*)d_in[19];
    const float* bb2w = (const float*)d_in[20];
    const float* bb2b = (const float*)d_in[21];
    const float* chw = (const float*)d_in[22];
    const float* chb = (const float*)d_in[23];
    const float* spw = (const float*)d_in[24];
    const float* spb = (const float*)d_in[25];
    const float* lcw = (const float*)d_in[26];
    const float* lcb = (const float*)d_in[27];
    const float* c1w = (const float*)d_in[28];
    const float* c1b = (const float*)d_in[29];
    const float* c2w = (const float*)d_in[30];
    const float* c2b = (const float*)d_in[31];

    float* out = (float*)d_out;
    float* ws = (float*)d_ws;
    float* naip2 = ws + WS_NAIP2;
    float* z_e = ws + WS_ZE;
    float* z_q = ws + WS_ZQ;
    float* h = ws + WS_H;
    float* e_sq = ws + WS_ESQ;
    float* parts = ws + WS_PART;
    int* counts = (int*)(ws + WS_CNTK);
    int* cntT = (int*)(ws + WS_CNTT);
    float* qtok = ws + WS_Q;
    int* cand = (int*)(ws + WS_CAND);
    unsigned short* zbf = (unsigned short*)(ws + WS_ZBF);
    unsigned short* cbbf = (unsigned short*)(ws + WS_CBBF);
    unsigned short* hbf = (unsigned short*)(ws + WS_HBF);
    unsigned short* wbf = (unsigned short*)(ws + WS_WBF);
    float2* esrc = (float2*)(ws + WS_ESRC);

    k_esq_zero<<<dim3(Kn / 256), dim3(256), 0, stream>>>(cb, e_sq, esrc, counts, cbbf);
    k_wcast<<<dim3(VSP_PAD * HIDn / 4 / 256), dim3(256), 0, stream>>>(spw, wbf);
    k_naip<<<dim3(Bn), dim3(128), 0, stream>>>(naip, conv_w, conv_b, npw, npb, naip2);
    k_ze<<<dim3(BTn / 16), dim3(256), 0, stream>>>(cont, cat, emb_sp, emb_lc, cpw, cpb, caw, cab,
                                                   f1w, f1b, f2w, f2b, naip2, z_e);
    k_zprep<<<dim3(BTn / 4), dim3(256), 0, stream>>>(z_e, zbf, qtok, cntT);
    k_vq_score2<<<dim3(VQ_Q, BTn / 64), dim3(256), 0, stream>>>(zbf, cbbf, esrc, qtok, cntT, cand);
    k_vq_rescore<<<dim3(BTn / 4), dim3(256), 0, stream>>>(cntT, cand, z_e, cb, e_sq, z_q,
                                                          out + O_IDX, counts, parts);
    k_backbone<<<dim3(BTn / 16), dim3(256), 0, stream>>>(z_q, bb1w, bb1b, bb2w, bb2b, chw, chb,
                                                         lcw, lcb, h, hbf, out + O_CONT, out + O_LC);
    k_sp_mfma<<<dim3(VSP_PAD / 128, BTn / 128), dim3(256), 0, stream>>>(hbf, wbf, spb, out + O_SP);
    k_canopy<<<dim3(Bn), dim3(128), 0, stream>>>(h, c1w, c1b, c2w, c2b, out + O_CAN);
    k_finalize<<<dim3(1), dim3(256), 0, stream>>>(parts, counts, out + O_LOSS, out + O_PPL);
}